// Round 9
// baseline (501.259 us; speedup 1.0000x reference)
//
#include <hip/hip_runtime.h>
#include <cstdint>
#include <cstddef>

// ---------------------------------------------------------------------------
// GraphAttentionHead: out = elu(softmax(mask(LeakyReLU(mu_i + xi_j))) @ h)
// Round 9: latency-tolerant B-staged attention GEMM.
//   k_bitmask: adj (268MB) -> 1-bit mask (8.4MB), HBM-roofline stream
//   k_gatt4:   256-thr blocks, 3/CU (12 waves, destaggered barriers);
//              wave 64i x 64n (mf=4 B-reuse, acc[4][4]=64 VGPR);
//              Bs dbuf 2x16KB, EfP packed bf16 E|F (2 b128/ksl);
//              bits from GLOBAL u64 w/ register prefetch (VMEM pipe);
//              truncating weight pack + in-GEMM Z via ones-MFMA
//              (identical weights -> common-mode, R7-verified numerics).
//   k_final:   sum 8 j-partials + 8 z-partials, /Z, ELU.
// R8 diagnosis: 12 b128 LDS per 16 MFMA at 8 lockstep waves/CU ->
// LDS-latency-exposed (~110us). Fix: mf=4 (6 b128/32 MFMA) + 3 blocks/CU.
// ---------------------------------------------------------------------------

#define LOG2E 1.44269504f

typedef __attribute__((ext_vector_type(8))) short short8;   // 8 bf16 = 4 VGPRs
typedef __attribute__((ext_vector_type(4))) float floatx4;  // MFMA acc

using uint_as1 = __attribute__((address_space(1))) unsigned int;
using uint_as3 = __attribute__((address_space(3))) unsigned int;

__device__ __forceinline__ void gld_lds16(const void* g, void* l) {
  __builtin_amdgcn_global_load_lds((const uint_as1*)g, (uint_as3*)l, 16, 0, 0);
}

__device__ __forceinline__ unsigned short f2b(float f) {  // fp32 -> bf16 RNE (finite)
  unsigned u = __float_as_uint(f);
  u += 0x7fffu + ((u >> 16) & 1u);
  return (unsigned short)(u >> 16);
}
__device__ __forceinline__ float b2f(short s) {
  return __uint_as_float(((unsigned)(unsigned short)s) << 16);
}

// ------------------- K_bm: adj int32 [8192x8192] -> bitmask ----------------
__global__ void k_bitmask(const int* __restrict__ adj, unsigned long long* __restrict__ bm) {
  int gw = (blockIdx.x * 256 + threadIdx.x) >> 6;
  int lane = threadIdx.x & 63;
  size_t w0 = (size_t)gw * 128;
  for (int r = 0; r < 128; r += 4) {
    size_t wd = w0 + r;
    int v0 = adj[(wd + 0) * 64 + lane];
    int v1 = adj[(wd + 1) * 64 + lane];
    int v2 = adj[(wd + 2) * 64 + lane];
    int v3 = adj[(wd + 3) * 64 + lane];
    unsigned long long m0 = __ballot(v0 != 0);
    unsigned long long m1 = __ballot(v1 != 0);
    unsigned long long m2 = __ballot(v2 != 0);
    unsigned long long m3 = __ballot(v3 != 0);
    if (lane == 0) {
      bm[wd] = m0; bm[wd + 1] = m1; bm[wd + 2] = m2; bm[wd + 3] = m3;
    }
  }
}

// --------------------------- K0a: features -> bf16 -------------------------
__global__ void k_cvt_features(const float* __restrict__ f, unsigned short* __restrict__ fb) {
  int tid = blockIdx.x * 256 + threadIdx.x;
  float4 v = ((const float4*)f)[tid];
  ushort4 o = {f2b(v.x), f2b(v.y), f2b(v.z), f2b(v.w)};
  *(ushort4*)&fb[tid * 4] = o;
}

// ------------------- K0b: W_phi [512][256] -> Wt bf16 [256][512] ------------
__global__ void k_prep_wt(const float* __restrict__ w, unsigned short* __restrict__ wt) {
  int tid = blockIdx.x * 256 + threadIdx.x;
  int n = tid >> 9, k = tid & 511;
  wt[n * 512 + k] = f2b(w[k * 256 + n]);
}

// ----------------- K0c: p_mu = W_phi @ w_mu, p_xi = W_phi @ w_xi ------------
__global__ void k_prep_p(const float* __restrict__ w, const float* __restrict__ wmu,
                         const float* __restrict__ wxi, float* __restrict__ pmu,
                         float* __restrict__ pxi) {
  int tid = blockIdx.x * 256 + threadIdx.x;
  int k = tid >> 2, seg = tid & 3;
  float sm = 0.f, sx = 0.f;
  int base = k * 256 + seg * 64;
#pragma unroll
  for (int c = 0; c < 64; c += 4) {
    float4 wv = *(const float4*)&w[base + c];
    float4 mv = *(const float4*)&wmu[seg * 64 + c];
    float4 xv = *(const float4*)&wxi[seg * 64 + c];
    sm += wv.x * mv.x + wv.y * mv.y + wv.z * mv.z + wv.w * mv.w;
    sx += wv.x * xv.x + wv.y * xv.y + wv.z * xv.z + wv.w * xv.w;
  }
  sm += __shfl_xor(sm, 1); sm += __shfl_xor(sm, 2);
  sx += __shfl_xor(sx, 1); sx += __shfl_xor(sx, 2);
  if (seg == 0) { pmu[k] = sm; pxi[k] = sx; }
}

// --- K2: mu/xi matvec, then store Emu=e^mu, Fmu=e^0.2mu, Exi, Fxi -----------
__global__ void k_mu_xi(const unsigned short* __restrict__ fb, const float* __restrict__ pmu,
                        const float* __restrict__ pxi, float* __restrict__ Emu,
                        float* __restrict__ Fmu, float* __restrict__ Exi,
                        float* __restrict__ Fxi) {
  int w = threadIdx.x >> 6, l = threadIdx.x & 63;
  int i = blockIdx.x * 4 + w;
  short8 fv = *(const short8*)&fb[i * 512 + l * 8];
  float m = 0.f, x = 0.f;
#pragma unroll
  for (int c = 0; c < 8; ++c) {
    float fvf = b2f(fv[c]);
    m = fmaf(fvf, pmu[l * 8 + c], m);
    x = fmaf(fvf, pxi[l * 8 + c], x);
  }
#pragma unroll
  for (int off = 32; off > 0; off >>= 1) {
    m += __shfl_xor(m, off);
    x += __shfl_xor(x, off);
  }
  if (l == 0) {
    float ms = m * LOG2E, xs = x * LOG2E;
    Emu[i] = __builtin_amdgcn_exp2f(ms);
    Fmu[i] = __builtin_amdgcn_exp2f(0.2f * ms);
    Exi[i] = __builtin_amdgcn_exp2f(xs);
    Fxi[i] = __builtin_amdgcn_exp2f(0.2f * xs);
  }
}

// ------------- K1: h_t[n][m] = (features @ W_phi)^T, bf16 MFMA --------------
__global__ __launch_bounds__(256, 2) void k_gemm1(const unsigned short* __restrict__ fb,
                                                  const unsigned short* __restrict__ wt,
                                                  unsigned short* __restrict__ ht) {
  __shared__ __align__(16) unsigned short As[64 * 64];
  __shared__ __align__(16) unsigned short Bs[128 * 64];
  int t = threadIdx.x, w = t >> 6, l = t & 63;
  int bm_ = blockIdx.x >> 1, bn = blockIdx.x & 1;
  int m0 = bm_ * 64, n0 = bn * 128;
  int lr = l >> 3, lg = l & 7, g = lg ^ lr;
  int kg = l >> 4, ln = l & 15;
  floatx4 zero = {0.f, 0.f, 0.f, 0.f};
  floatx4 acc[4][2];
#pragma unroll
  for (int mf = 0; mf < 4; ++mf)
#pragma unroll
    for (int nf = 0; nf < 2; ++nf) acc[mf][nf] = zero;

  for (int it = 0; it < 8; ++it) {
    int k0 = it * 64;
#pragma unroll
    for (int q = 0; q < 2; ++q) {
      int row = w * 16 + q * 8 + lr;
      const void* gp = fb + (size_t)(m0 + row) * 512 + k0 + g * 8;
      int lb = __builtin_amdgcn_readfirstlane((w * 16 + q * 8) * 64);
      gld_lds16(gp, &As[lb]);
    }
#pragma unroll
    for (int q = 0; q < 4; ++q) {
      int row = w * 32 + q * 8 + lr;
      const void* gp = wt + (size_t)(n0 + row) * 512 + k0 + g * 8;
      int lb = __builtin_amdgcn_readfirstlane((w * 32 + q * 8) * 64);
      gld_lds16(gp, &Bs[lb]);
    }
    __syncthreads();
#pragma unroll
    for (int ks = 0; ks < 2; ++ks) {
      int gg = ks * 4 + kg;
      int swz = (gg ^ (ln & 7)) * 8;
      short8 bfr[2];
#pragma unroll
      for (int nf = 0; nf < 2; ++nf)
        bfr[nf] = *(const short8*)&Bs[(w * 32 + nf * 16 + ln) * 64 + swz];
#pragma unroll
      for (int mf = 0; mf < 4; ++mf) {
        short8 afr = *(const short8*)&As[(mf * 16 + ln) * 64 + swz];
#pragma unroll
        for (int nf = 0; nf < 2; ++nf)
          acc[mf][nf] = __builtin_amdgcn_mfma_f32_16x16x32_bf16(afr, bfr[nf], acc[mf][nf], 0, 0, 0);
      }
    }
    __syncthreads();
  }
#pragma unroll
  for (int mf = 0; mf < 4; ++mf)
#pragma unroll
    for (int nf = 0; nf < 2; ++nf) {
      int ng = n0 + w * 32 + nf * 16 + ln;
      int mg = m0 + mf * 16 + kg * 4;
      ushort4 o = {f2b(acc[mf][nf][0]), f2b(acc[mf][nf][1]),
                   f2b(acc[mf][nf][2]), f2b(acc[mf][nf][3])};
      *(ushort4*)&ht[(size_t)ng * 8192 + mg] = o;
    }
}

// ------------- K3: attention GEMM, 3 blocks/CU, mf=4 B-reuse ----------------
// grid 1024 = 64 ig x 2 nb x 8 jb. Block 128i x 128n x 1024j; 4 waves;
// wave 64i x 64n (mf=4, nf=4). 16 half-windows of 64j, Bs dbuf, 1 barrier/hw.
// Weights: bit ? max(EM*E, FM*F) : 0, truncating bf16 pack; Z via ones-MFMA
// on the SAME weights (common-mode). Bits prefetched from global u64.
__global__ __launch_bounds__(256, 3) void k_gatt4(const unsigned long long* __restrict__ bm64,
                                                  const unsigned short* __restrict__ ht,
                                                  const float* __restrict__ Emu,
                                                  const float* __restrict__ Fmu,
                                                  const float* __restrict__ Exi,
                                                  const float* __restrict__ Fxi,
                                                  float* __restrict__ nump,
                                                  float* __restrict__ zpart) {
  __shared__ __align__(16) unsigned short Bs[2][128 * 64];  // 32 KB
  __shared__ __align__(16) unsigned int EfP[1024];          // 4 KB packed E|F bf16

  int t = threadIdx.x, w = t >> 6, l = t & 63;
  int ln = l & 15, kg = l >> 4;
  int wi = w >> 1, wn = w & 1;
  int b = blockIdx.x;
  int jb = b & 7, nb = (b >> 3) & 1, ig = b >> 4;
  int i0 = ig * 128, n0 = nb * 128, jc0 = jb * 1024;

  // ---- prologue: pack EfP[j] = (Ebits>>16) | (Fbits&0xffff0000) ----
  {
    float4 e = *(const float4*)&Exi[jc0 + t * 4];
    float4 f = *(const float4*)&Fxi[jc0 + t * 4];
    uint4 p;
    p.x = (__float_as_uint(f.x) & 0xffff0000u) | (__float_as_uint(e.x) >> 16);
    p.y = (__float_as_uint(f.y) & 0xffff0000u) | (__float_as_uint(e.y) >> 16);
    p.z = (__float_as_uint(f.z) & 0xffff0000u) | (__float_as_uint(e.z) >> 16);
    p.w = (__float_as_uint(f.w) & 0xffff0000u) | (__float_as_uint(e.w) >> 16);
    *(uint4*)&EfP[t * 4] = p;
  }

  float EM[4], FM[4];
#pragma unroll
  for (int mf = 0; mf < 4; ++mf) {
    int i = i0 + wi * 64 + mf * 16 + ln;
    EM[mf] = Emu[i];
    FM[mf] = Fmu[i];
  }

  floatx4 zero = {0.f, 0.f, 0.f, 0.f};
  floatx4 acc[4][4];
#pragma unroll
  for (int mf = 0; mf < 4; ++mf)
#pragma unroll
    for (int nf = 0; nf < 4; ++nf) acc[mf][nf] = zero;
  floatx4 accz[4];
#pragma unroll
  for (int mf = 0; mf < 4; ++mf) accz[mf] = zero;

  short8 ones;
#pragma unroll
  for (int e = 0; e < 8; ++e) ones[e] = (short)0x3F80;  // bf16 1.0

  // bits row pointers (u64 per 64j half-window)
  const unsigned long long* bp[4];
#pragma unroll
  for (int mf = 0; mf < 4; ++mf)
    bp[mf] = bm64 + (size_t)(i0 + wi * 64 + mf * 16 + ln) * 128 + jb * 16;

  // stage B half-window hw into buffer b_: 128 rows x 128B, 4 gld/wave
#define STAGE(hw_, b_)                                                        \
  {                                                                           \
    int j0_ = jc0 + (hw_) * 64;                                               \
    _Pragma("unroll")                                                         \
    for (int q = 0; q < 4; ++q) {                                             \
      int r0 = w * 32 + q * 8;                                                \
      int row = r0 + (l >> 3);                                                \
      int g = (l & 7) ^ (row & 7);                                            \
      const void* gp = ht + (size_t)(n0 + row) * 8192 + j0_ + g * 8;          \
      int lb = __builtin_amdgcn_readfirstlane((b_) * (128 * 64) + r0 * 64);   \
      gld_lds16(gp, &Bs[0][lb]);                                              \
    }                                                                         \
  }

  unsigned long long bc[4], bnx[4];
#pragma unroll
  for (int mf = 0; mf < 4; ++mf) bc[mf] = bp[mf][0];
  STAGE(0, 0);
  __syncthreads();  // EfP writes + staging(0) drained

  for (int hw = 0; hw < 16; ++hw) {
    int buf = hw & 1;
    if (hw < 15) {
      STAGE(hw + 1, buf ^ 1);                 // overlaps compute on buf
#pragma unroll
      for (int mf = 0; mf < 4; ++mf) bnx[mf] = bp[mf][hw + 1];  // L2 prefetch
    }
#pragma unroll
    for (int ksl = 0; ksl < 2; ++ksl) {
      int gran = ksl * 4 + kg;                // granule 0..7 within 64j
      int jl = hw * 64 + gran * 8;
      uint4 p0 = *(const uint4*)&EfP[jl];
      uint4 p1 = *(const uint4*)&EfP[jl + 4];
      unsigned pe[8] = {p0.x, p0.y, p0.z, p0.w, p1.x, p1.y, p1.z, p1.w};
      short8 bfv[4];
#pragma unroll
      for (int nf = 0; nf < 4; ++nf) {
        int n = wn * 64 + nf * 16 + ln;
        bfv[nf] = *(const short8*)&Bs[buf][n * 64 + ((gran ^ (n & 7)) * 8)];
      }
#pragma unroll
      for (int mf = 0; mf < 4; ++mf) {
        unsigned bits = (unsigned)(bc[mf] >> (ksl * 32));
        bits = (bits >> (kg * 8)) & 0xffu;
        float A = EM[mf], F = FM[mf];
        float vv[8];
#pragma unroll
        for (int e = 0; e < 8; ++e) {
          float Ef = __uint_as_float(pe[e] << 16);
          float Ff = __uint_as_float(pe[e] & 0xffff0000u);
          float m = fmaxf(A * Ef, F * Ff);
          vv[e] = (bits & (1u << e)) ? m : 0.f;
        }
        union { uint4 u; short8 s; } cv;  // truncating pack
        cv.u.x = (__float_as_uint(vv[1]) & 0xffff0000u) | (__float_as_uint(vv[0]) >> 16);
        cv.u.y = (__float_as_uint(vv[3]) & 0xffff0000u) | (__float_as_uint(vv[2]) >> 16);
        cv.u.z = (__float_as_uint(vv[5]) & 0xffff0000u) | (__float_as_uint(vv[4]) >> 16);
        cv.u.w = (__float_as_uint(vv[7]) & 0xffff0000u) | (__float_as_uint(vv[6]) >> 16);
        short8 af = cv.s;
        accz[mf] = __builtin_amdgcn_mfma_f32_16x16x32_bf16(af, ones, accz[mf], 0, 0, 0);
#pragma unroll
        for (int nf = 0; nf < 4; ++nf)
          acc[mf][nf] = __builtin_amdgcn_mfma_f32_16x16x32_bf16(af, bfv[nf], acc[mf][nf], 0, 0, 0);
      }
    }
    __syncthreads();  // reads of buf done; staging(hw+1) drained
#pragma unroll
    for (int mf = 0; mf < 4; ++mf) bc[mf] = bnx[mf];
  }
#undef STAGE

  // ---- epilogue: numerator partial + Z partial (plain stores) ----
  float* np = nump + (size_t)jb * (8192 * 256);
#pragma unroll
  for (int mf = 0; mf < 4; ++mf) {
    int rowb = i0 + wi * 64 + mf * 16 + kg * 4;
#pragma unroll
    for (int r = 0; r < 4; ++r) {
      float* rp = np + (size_t)(rowb + r) * 256 + n0 + wn * 64;
#pragma unroll
      for (int nf = 0; nf < 4; ++nf)
        rp[nf * 16 + ln] = acc[mf][nf][r];
    }
    if (wn == 0 && ln == 0) {  // nb=0/1 write identical values (benign)
#pragma unroll
      for (int r = 0; r < 4; ++r)
        zpart[jb * 8192 + rowb + r] = accz[mf][r];
    }
  }
}

// ---------------- K4: finalize: sum 8 partials, /Z, ELU ---------------------
__global__ void k_final(const float* __restrict__ nump, const float* __restrict__ zpart,
                        float* __restrict__ out) {
  int tid = blockIdx.x * 256 + threadIdx.x;  // x4 floats
  int i = tid >> 6;
  float z = 0.f;
#pragma unroll
  for (int p = 0; p < 8; ++p) z += zpart[p * 8192 + i];
  float zi = 1.0f / z;
  float4 v = {0.f, 0.f, 0.f, 0.f};
#pragma unroll
  for (int p = 0; p < 8; ++p) {
    float4 s = *(const float4*)&nump[(size_t)p * (8192 * 256) + tid * 4];
    v.x += s.x; v.y += s.y; v.z += s.z; v.w += s.w;
  }
  v.x *= zi; v.y *= zi; v.z *= zi; v.w *= zi;
  v.x = (v.x > 0.f) ? v.x : (__builtin_amdgcn_exp2f(v.x * LOG2E) - 1.f);
  v.y = (v.y > 0.f) ? v.y : (__builtin_amdgcn_exp2f(v.y * LOG2E) - 1.f);
  v.z = (v.z > 0.f) ? v.z : (__builtin_amdgcn_exp2f(v.z * LOG2E) - 1.f);
  v.w = (v.w > 0.f) ? v.w : (__builtin_amdgcn_exp2f(v.w * LOG2E) - 1.f);
  *(float4*)&out[tid * 4] = v;
}

// ---------------------------------------------------------------------------
extern "C" void kernel_launch(void* const* d_in, const int* in_sizes, int n_in,
                              void* d_out, int out_size, void* d_ws, size_t ws_size,
                              hipStream_t stream) {
  const float* features = (const float*)d_in[0];
  const int* adjm = (const int*)d_in[1];
  const float* W_phi = (const float*)d_in[2];
  const float* w_mu = (const float*)d_in[3];
  const float* w_xi = (const float*)d_in[4];
  float* out = (float*)d_out;

  char* ws = (char*)d_ws;
  unsigned short* fb  = (unsigned short*)(ws + 0);         // 8192x512 bf16 = 8 MB
  unsigned short* ht  = (unsigned short*)(ws + 8388608);   // 256x8192 bf16 = 4 MB
  unsigned short* wt  = (unsigned short*)(ws + 12582912);  // 256x512 bf16 = 256 KB
  float* pmu = (float*)(ws + 12845056);                    // 512 f32
  float* pxi = (float*)(ws + 12847104);                    // 512 f32
  float* Emu = (float*)(ws + 12849152);                    // 8192 f32 each
  float* Fmu = (float*)(ws + 12881920);
  float* Exi = (float*)(ws + 12914688);
  float* Fxi = (float*)(ws + 12947456);
  unsigned long long* bmask = (unsigned long long*)(ws + 13631488);  // 8 MB
  float* zpart = (float*)(ws + 22020096);                  // 8 x 8192 f32
  float* nump  = (float*)(ws + 25165824);                  // 8 x 8 MB partials

  k_cvt_features<<<4096, 256, 0, stream>>>(features, fb);
  k_prep_wt<<<512, 256, 0, stream>>>(W_phi, wt);
  k_prep_p<<<8, 256, 0, stream>>>(W_phi, w_mu, w_xi, pmu, pxi);
  k_mu_xi<<<2048, 256, 0, stream>>>(fb, pmu, pxi, Emu, Fmu, Exi, Fxi);
  k_gemm1<<<256, 256, 0, stream>>>(fb, wt, ht);
  k_bitmask<<<2048, 256, 0, stream>>>(adjm, bmask);
  k_gatt4<<<1024, 256, 0, stream>>>(bmask, ht, Emu, Fmu, Exi, Fxi, nump, zpart);
  k_final<<<2048, 256, 0, stream>>>(nump, zpart, out);
}

// Round 10
// 471.038 us; speedup vs baseline: 1.0642x; 1.0642x over previous
//
#include <hip/hip_runtime.h>
#include <cstdint>
#include <cstddef>

// ---------------------------------------------------------------------------
// GraphAttentionHead: out = elu(softmax(mask(LeakyReLU(mu_i + xi_j))) @ h)
// Round 10: R8 winner, serial-pipe-sum minimized.
//   k_bitmaskz: adj stream -> bitmask + fp32 Z rowsums (HBM roofline)
//   k_gatt5:    512 thr, 8 waves ALL i-split (wave 32i x 256n) -> weight
//               build duplication 1x (VALU 15->7.5us). acc[2][16]=128 VGPR,
//               bfv in two halves (~220 VGPR < 256 cap). Bits staged ONCE
//               per block (32KB, XOR-swizzled u64 -> 2-way free), E/F once
//               (16KB), Bs dbuf 2x32KB; 112KB LDS, 1 block/CU, jb<->XCD.
//   k_final:    sum 8 j-partials, /Z, ELU.
// Calibration: R3 profile showed pipes match models exactly; kernels idle
// 55-75% on dependency stalls. R8 = 60us serial sum -> 110us (55% eff).
// gatt5 = 46us serial sum -> predict 80-95us.
// ---------------------------------------------------------------------------

#define LOG2E 1.44269504f

typedef __attribute__((ext_vector_type(8))) short short8;   // 8 bf16 = 4 VGPRs
typedef __attribute__((ext_vector_type(4))) float floatx4;  // MFMA acc

using uint_as1 = __attribute__((address_space(1))) unsigned int;
using uint_as3 = __attribute__((address_space(3))) unsigned int;

__device__ __forceinline__ void gld_lds16(const void* g, void* l) {
  __builtin_amdgcn_global_load_lds((const uint_as1*)g, (uint_as3*)l, 16, 0, 0);
}

__device__ __forceinline__ unsigned short f2b(float f) {  // fp32 -> bf16 RNE (finite)
  unsigned u = __float_as_uint(f);
  u += 0x7fffu + ((u >> 16) & 1u);
  return (unsigned short)(u >> 16);
}
__device__ __forceinline__ float b2f(short s) {
  return __uint_as_float(((unsigned)(unsigned short)s) << 16);
}

// -------- K_bmz: adj -> bitmask + Z rowsums (one wave per row) -------------
__global__ void k_bitmaskz(const int* __restrict__ adj,
                           const float* __restrict__ Emu, const float* __restrict__ Fmu,
                           const float* __restrict__ Exi, const float* __restrict__ Fxi,
                           unsigned long long* __restrict__ bm, float* __restrict__ zbuf) {
  int gw = (blockIdx.x * 256 + threadIdx.x) >> 6;   // row i
  int lane = threadIdx.x & 63;
  float EM = Emu[gw], FM = Fmu[gw];
  size_t w0 = (size_t)gw * 128;
  float z = 0.f;
  for (int r = 0; r < 128; r += 4) {
    size_t wd = w0 + r;
    int v0 = adj[(wd + 0) * 64 + lane];
    int v1 = adj[(wd + 1) * 64 + lane];
    int v2 = adj[(wd + 2) * 64 + lane];
    int v3 = adj[(wd + 3) * 64 + lane];
    float e0 = Exi[(r + 0) * 64 + lane], f0 = Fxi[(r + 0) * 64 + lane];
    float e1 = Exi[(r + 1) * 64 + lane], f1 = Fxi[(r + 1) * 64 + lane];
    float e2 = Exi[(r + 2) * 64 + lane], f2 = Fxi[(r + 2) * 64 + lane];
    float e3 = Exi[(r + 3) * 64 + lane], f3 = Fxi[(r + 3) * 64 + lane];
    unsigned long long m0 = __ballot(v0 != 0);
    unsigned long long m1 = __ballot(v1 != 0);
    unsigned long long m2 = __ballot(v2 != 0);
    unsigned long long m3 = __ballot(v3 != 0);
    z += (v0 != 0) ? fmaxf(EM * e0, FM * f0) : 0.f;
    z += (v1 != 0) ? fmaxf(EM * e1, FM * f1) : 0.f;
    z += (v2 != 0) ? fmaxf(EM * e2, FM * f2) : 0.f;
    z += (v3 != 0) ? fmaxf(EM * e3, FM * f3) : 0.f;
    if (lane == 0) {
      bm[wd] = m0; bm[wd + 1] = m1; bm[wd + 2] = m2; bm[wd + 3] = m3;
    }
  }
#pragma unroll
  for (int off = 32; off > 0; off >>= 1) z += __shfl_xor(z, off);
  if (lane == 0) zbuf[gw] = z;
}

// --------------------------- K0a: features -> bf16 -------------------------
__global__ void k_cvt_features(const float* __restrict__ f, unsigned short* __restrict__ fb) {
  int tid = blockIdx.x * 256 + threadIdx.x;
  float4 v = ((const float4*)f)[tid];
  ushort4 o = {f2b(v.x), f2b(v.y), f2b(v.z), f2b(v.w)};
  *(ushort4*)&fb[tid * 4] = o;
}

// ------------------- K0b: W_phi [512][256] -> Wt bf16 [256][512] ------------
__global__ void k_prep_wt(const float* __restrict__ w, unsigned short* __restrict__ wt) {
  int tid = blockIdx.x * 256 + threadIdx.x;
  int n = tid >> 9, k = tid & 511;
  wt[n * 512 + k] = f2b(w[k * 256 + n]);
}

// ----------------- K0c: p_mu = W_phi @ w_mu, p_xi = W_phi @ w_xi ------------
__global__ void k_prep_p(const float* __restrict__ w, const float* __restrict__ wmu,
                         const float* __restrict__ wxi, float* __restrict__ pmu,
                         float* __restrict__ pxi) {
  int tid = blockIdx.x * 256 + threadIdx.x;
  int k = tid >> 2, seg = tid & 3;
  float sm = 0.f, sx = 0.f;
  int base = k * 256 + seg * 64;
#pragma unroll
  for (int c = 0; c < 64; c += 4) {
    float4 wv = *(const float4*)&w[base + c];
    float4 mv = *(const float4*)&wmu[seg * 64 + c];
    float4 xv = *(const float4*)&wxi[seg * 64 + c];
    sm += wv.x * mv.x + wv.y * mv.y + wv.z * mv.z + wv.w * mv.w;
    sx += wv.x * xv.x + wv.y * xv.y + wv.z * xv.z + wv.w * xv.w;
  }
  sm += __shfl_xor(sm, 1); sm += __shfl_xor(sm, 2);
  sx += __shfl_xor(sx, 1); sx += __shfl_xor(sx, 2);
  if (seg == 0) { pmu[k] = sm; pxi[k] = sx; }
}

// --- K2: mu/xi matvec, then store Emu=e^mu, Fmu=e^0.2mu, Exi, Fxi -----------
__global__ void k_mu_xi(const unsigned short* __restrict__ fb, const float* __restrict__ pmu,
                        const float* __restrict__ pxi, float* __restrict__ Emu,
                        float* __restrict__ Fmu, float* __restrict__ Exi,
                        float* __restrict__ Fxi) {
  int w = threadIdx.x >> 6, l = threadIdx.x & 63;
  int i = blockIdx.x * 4 + w;
  short8 fv = *(const short8*)&fb[i * 512 + l * 8];
  float m = 0.f, x = 0.f;
#pragma unroll
  for (int c = 0; c < 8; ++c) {
    float fvf = b2f(fv[c]);
    m = fmaf(fvf, pmu[l * 8 + c], m);
    x = fmaf(fvf, pxi[l * 8 + c], x);
  }
#pragma unroll
  for (int off = 32; off > 0; off >>= 1) {
    m += __shfl_xor(m, off);
    x += __shfl_xor(x, off);
  }
  if (l == 0) {
    float ms = m * LOG2E, xs = x * LOG2E;
    Emu[i] = __builtin_amdgcn_exp2f(ms);
    Fmu[i] = __builtin_amdgcn_exp2f(0.2f * ms);
    Exi[i] = __builtin_amdgcn_exp2f(xs);
    Fxi[i] = __builtin_amdgcn_exp2f(0.2f * xs);
  }
}

// ------------- K1: h_t[n][m] = (features @ W_phi)^T, bf16 MFMA --------------
__global__ __launch_bounds__(256, 2) void k_gemm1(const unsigned short* __restrict__ fb,
                                                  const unsigned short* __restrict__ wt,
                                                  unsigned short* __restrict__ ht) {
  __shared__ __align__(16) unsigned short As[64 * 64];
  __shared__ __align__(16) unsigned short Bs[128 * 64];
  int t = threadIdx.x, w = t >> 6, l = t & 63;
  int bm_ = blockIdx.x >> 1, bn = blockIdx.x & 1;
  int m0 = bm_ * 64, n0 = bn * 128;
  int lr = l >> 3, lg = l & 7, g = lg ^ lr;
  int kg = l >> 4, ln = l & 15;
  floatx4 zero = {0.f, 0.f, 0.f, 0.f};
  floatx4 acc[4][2];
#pragma unroll
  for (int mf = 0; mf < 4; ++mf)
#pragma unroll
    for (int nf = 0; nf < 2; ++nf) acc[mf][nf] = zero;

  for (int it = 0; it < 8; ++it) {
    int k0 = it * 64;
#pragma unroll
    for (int q = 0; q < 2; ++q) {
      int row = w * 16 + q * 8 + lr;
      const void* gp = fb + (size_t)(m0 + row) * 512 + k0 + g * 8;
      int lb = __builtin_amdgcn_readfirstlane((w * 16 + q * 8) * 64);
      gld_lds16(gp, &As[lb]);
    }
#pragma unroll
    for (int q = 0; q < 4; ++q) {
      int row = w * 32 + q * 8 + lr;
      const void* gp = wt + (size_t)(n0 + row) * 512 + k0 + g * 8;
      int lb = __builtin_amdgcn_readfirstlane((w * 32 + q * 8) * 64);
      gld_lds16(gp, &Bs[lb]);
    }
    __syncthreads();
#pragma unroll
    for (int ks = 0; ks < 2; ++ks) {
      int gg = ks * 4 + kg;
      int swz = (gg ^ (ln & 7)) * 8;
      short8 bfr[2];
#pragma unroll
      for (int nf = 0; nf < 2; ++nf)
        bfr[nf] = *(const short8*)&Bs[(w * 32 + nf * 16 + ln) * 64 + swz];
#pragma unroll
      for (int mf = 0; mf < 4; ++mf) {
        short8 afr = *(const short8*)&As[(mf * 16 + ln) * 64 + swz];
#pragma unroll
        for (int nf = 0; nf < 2; ++nf)
          acc[mf][nf] = __builtin_amdgcn_mfma_f32_16x16x32_bf16(afr, bfr[nf], acc[mf][nf], 0, 0, 0);
      }
    }
    __syncthreads();
  }
#pragma unroll
  for (int mf = 0; mf < 4; ++mf)
#pragma unroll
    for (int nf = 0; nf < 2; ++nf) {
      int ng = n0 + w * 32 + nf * 16 + ln;
      int mg = m0 + mf * 16 + kg * 4;
      ushort4 o = {f2b(acc[mf][nf][0]), f2b(acc[mf][nf][1]),
                   f2b(acc[mf][nf][2]), f2b(acc[mf][nf][3])};
      *(ushort4*)&ht[(size_t)ng * 8192 + mg] = o;
    }
}

// ------------- K3: attention GEMM, dup-free i-split waves -------------------
// grid 256 = 8 jb x 32 ig (jb<->XCD). Block 256i x 256n x 1024j; 8 waves,
// wave 32i x 256n (mf=2, nf=16 in two halves), acc[2][16]=128 VGPR.
// Bits (32KB) + E/F (16KB) staged once; Bs dbuf 2x32KB; 16 hw of 64j,
// 1 barrier each. Weights: bit ? max(EM*E, FM*F) : 0, RNE pack. Z external.
__global__ __launch_bounds__(512, 2) void k_gatt5(const unsigned char* __restrict__ bm8,
                                                  const unsigned short* __restrict__ ht,
                                                  const float* __restrict__ Emu,
                                                  const float* __restrict__ Fmu,
                                                  const float* __restrict__ Exi,
                                                  const float* __restrict__ Fxi,
                                                  float* __restrict__ nump) {
  __shared__ __align__(16) unsigned short Bs[2][256 * 64];   // 64 KB
  __shared__ __align__(16) unsigned char BitAll[256 * 128];  // 32 KB (XOR-swizzled)
  __shared__ __align__(16) float EfE[1024];                  // 8 KB
  __shared__ __align__(16) float EfF[1024];                  // 8 KB

  int t = threadIdx.x, w = t >> 6, l = t & 63;
  int ln = l & 15, kg = l >> 4;
  int jb = blockIdx.x & 7, ig = blockIdx.x >> 3;
  int i0 = ig * 256;
  int jc0 = jb * 1024;

  // ---- prologue staging ----
  // E/F (fp32, 4KB each half of thread pool)
  if (t < 256) {
    *(float4*)&EfE[t * 4] = *(const float4*)&Exi[jc0 + t * 4];
  } else {
    int t2 = t - 256;
    *(float4*)&EfF[t2 * 4] = *(const float4*)&Fxi[jc0 + t2 * 4];
  }
  // Bits: 2048 16B-chunks, XOR-granule swizzle (phys g' holds logical g'^(row&7))
#pragma unroll
  for (int r = 0; r < 4; ++r) {
    int c = r * 512 + t;
    int row = c >> 3, gp_ = c & 7;
    int g = gp_ ^ (row & 7);
    const void* src = bm8 + (size_t)(i0 + row) * 1024 + jb * 128 + g * 16;
    int lb = __builtin_amdgcn_readfirstlane((r * 512 + w * 64) * 16);
    gld_lds16(src, &BitAll[lb]);
  }

  float EM[2], FM[2];
#pragma unroll
  for (int mf = 0; mf < 2; ++mf) {
    int i = i0 + w * 32 + mf * 16 + ln;
    EM[mf] = Emu[i];
    FM[mf] = Fmu[i];
  }

  floatx4 zero = {0.f, 0.f, 0.f, 0.f};
  floatx4 acc[2][16];
#pragma unroll
  for (int mf = 0; mf < 2; ++mf)
#pragma unroll
    for (int nf = 0; nf < 16; ++nf) acc[mf][nf] = zero;

  // stage Bs half-window hw_ (64j x 256n) into buffer b_: 4 rounds/wave
#define STAGE(hw_, b_)                                                        \
  {                                                                           \
    int j0_ = jc0 + (hw_) * 64;                                               \
    _Pragma("unroll")                                                         \
    for (int q = 0; q < 4; ++q) {                                             \
      int r0 = w * 32 + q * 8;                                                \
      int row = r0 + (l >> 3);                                                \
      int g = (l & 7) ^ (row & 7);                                            \
      const void* gp = ht + (size_t)row * 8192 + j0_ + g * 8;                 \
      int lb = __builtin_amdgcn_readfirstlane((b_) * (256 * 64) + r0 * 64);   \
      gld_lds16(gp, &Bs[0][lb]);                                              \
    }                                                                         \
  }

  STAGE(0, 0);
  __syncthreads();  // prologue + staging(0) drained

  for (int hw = 0; hw < 16; ++hw) {
    int buf = hw & 1;
    if (hw < 15) STAGE(hw + 1, buf ^ 1);  // overlaps compute on buf

    // bits u64 per (mf): XOR-swizzled read (2-way bank = free)
    unsigned long long bw[2];
#pragma unroll
    for (int mf = 0; mf < 2; ++mf) {
      int rowL = w * 32 + mf * 16 + ln;
      bw[mf] = *(const unsigned long long*)
          &BitAll[rowL * 128 + (((hw >> 1) ^ (rowL & 7)) * 16) + (hw & 1) * 8];
    }

#pragma unroll
    for (int ksl = 0; ksl < 2; ++ksl) {
      int gran = ksl * 4 + kg;            // granule 0..7 within 64j
      int jl = hw * 64 + gran * 8;
      float4 e0 = *(const float4*)&EfE[jl];
      float4 e1 = *(const float4*)&EfE[jl + 4];
      float4 f0 = *(const float4*)&EfF[jl];
      float4 f1 = *(const float4*)&EfF[jl + 4];
      float ex[8] = {e0.x, e0.y, e0.z, e0.w, e1.x, e1.y, e1.z, e1.w};
      float fx[8] = {f0.x, f0.y, f0.z, f0.w, f1.x, f1.y, f1.z, f1.w};
      // build A-frags (RNE pack)
      short8 af[2];
#pragma unroll
      for (int mf = 0; mf < 2; ++mf) {
        unsigned bits = (unsigned)(bw[mf] >> ((ksl * 4 + kg) * 8)) & 0xffu;
        float A = EM[mf], F = FM[mf];
#pragma unroll
        for (int e = 0; e < 8; ++e) {
          float m = fmaxf(A * ex[e], F * fx[e]);
          m = (bits & (1u << e)) ? m : 0.f;
          af[mf][e] = (short)f2b(m);
        }
      }
      // two halves of 8 B-frags each (limits live VGPRs)
#pragma unroll
      for (int half = 0; half < 2; ++half) {
        short8 bfv[8];
#pragma unroll
        for (int nf = 0; nf < 8; ++nf) {
          int n = half * 128 + nf * 16 + ln;
          bfv[nf] = *(const short8*)&Bs[buf][n * 64 + ((gran ^ (n & 7)) * 8)];
        }
#pragma unroll
        for (int mf = 0; mf < 2; ++mf)
#pragma unroll
          for (int nf = 0; nf < 8; ++nf)
            acc[mf][half * 8 + nf] = __builtin_amdgcn_mfma_f32_16x16x32_bf16(
                af[mf], bfv[nf], acc[mf][half * 8 + nf], 0, 0, 0);
      }
    }
    __syncthreads();  // reads of buf done; staging(hw+1) drained
  }
#undef STAGE

  // ---- epilogue: numerator partial (plain stores) ----
  float* np = nump + (size_t)jb * (8192 * 256);
#pragma unroll
  for (int mf = 0; mf < 2; ++mf) {
    int rowb = i0 + w * 32 + mf * 16 + kg * 4;
#pragma unroll
    for (int r = 0; r < 4; ++r) {
      float* rp = np + (size_t)(rowb + r) * 256;
#pragma unroll
      for (int nf = 0; nf < 16; ++nf)
        rp[nf * 16 + ln] = acc[mf][nf][r];
    }
  }
}

// ---------------- K4: finalize: sum 8 j-partials, /Z, ELU -------------------
__global__ void k_final(const float* __restrict__ nump, const float* __restrict__ zbuf,
                        float* __restrict__ out) {
  int tid = blockIdx.x * 256 + threadIdx.x;  // x4 floats
  int i = tid >> 6;
  float zi = 1.0f / zbuf[i];
  float4 v = {0.f, 0.f, 0.f, 0.f};
#pragma unroll
  for (int p = 0; p < 8; ++p) {
    float4 s = *(const float4*)&nump[(size_t)p * (8192 * 256) + tid * 4];
    v.x += s.x; v.y += s.y; v.z += s.z; v.w += s.w;
  }
  v.x *= zi; v.y *= zi; v.z *= zi; v.w *= zi;
  v.x = (v.x > 0.f) ? v.x : (__builtin_amdgcn_exp2f(v.x * LOG2E) - 1.f);
  v.y = (v.y > 0.f) ? v.y : (__builtin_amdgcn_exp2f(v.y * LOG2E) - 1.f);
  v.z = (v.z > 0.f) ? v.z : (__builtin_amdgcn_exp2f(v.z * LOG2E) - 1.f);
  v.w = (v.w > 0.f) ? v.w : (__builtin_amdgcn_exp2f(v.w * LOG2E) - 1.f);
  *(float4*)&out[tid * 4] = v;
}

// ---------------------------------------------------------------------------
extern "C" void kernel_launch(void* const* d_in, const int* in_sizes, int n_in,
                              void* d_out, int out_size, void* d_ws, size_t ws_size,
                              hipStream_t stream) {
  const float* features = (const float*)d_in[0];
  const int* adjm = (const int*)d_in[1];
  const float* W_phi = (const float*)d_in[2];
  const float* w_mu = (const float*)d_in[3];
  const float* w_xi = (const float*)d_in[4];
  float* out = (float*)d_out;

  char* ws = (char*)d_ws;
  unsigned short* fb  = (unsigned short*)(ws + 0);         // 8192x512 bf16 = 8 MB
  unsigned short* ht  = (unsigned short*)(ws + 8388608);   // 256x8192 bf16 = 4 MB
  unsigned short* wt  = (unsigned short*)(ws + 12582912);  // 256x512 bf16 = 256 KB
  float* pmu = (float*)(ws + 12845056);                    // 512 f32
  float* pxi = (float*)(ws + 12847104);                    // 512 f32
  float* Emu = (float*)(ws + 12849152);                    // 8192 f32 each
  float* Fmu = (float*)(ws + 12881920);
  float* Exi = (float*)(ws + 12914688);
  float* Fxi = (float*)(ws + 12947456);
  float* zbuf = (float*)(ws + 12980224);                   // 8192 f32
  unsigned char* bmask = (unsigned char*)(ws + 13631488);  // 8 MB bitmask
  float* nump = (float*)(ws + 25165824);                   // 8 x 8 MB partials

  k_cvt_features<<<4096, 256, 0, stream>>>(features, fb);
  k_prep_wt<<<512, 256, 0, stream>>>(W_phi, wt);
  k_prep_p<<<8, 256, 0, stream>>>(W_phi, w_mu, w_xi, pmu, pxi);
  k_mu_xi<<<2048, 256, 0, stream>>>(fb, pmu, pxi, Emu, Fmu, Exi, Fxi);
  k_gemm1<<<256, 256, 0, stream>>>(fb, wt, ht);
  k_bitmaskz<<<2048, 256, 0, stream>>>(adjm, Emu, Fmu, Exi, Fxi,
                                       (unsigned long long*)bmask, zbuf);
  k_gatt5<<<256, 512, 0, stream>>>(bmask, ht, Emu, Fmu, Exi, Fxi, nump);
  k_final<<<2048, 256, 0, stream>>>(nump, zbuf, out);
}

// Round 11
// 465.694 us; speedup vs baseline: 1.0764x; 1.0115x over previous
//
#include <hip/hip_runtime.h>
#include <cstdint>
#include <cstddef>

// ---------------------------------------------------------------------------
// GraphAttentionHead: out = elu(softmax(mask(LeakyReLU(mu_i + xi_j))) @ h)
// Round 11: R10 winner with stall reduction.
//   k_gatt6: windows 128j (8 barriers vs 16), Bs dbuf 2x64KB, bits via
//            register global_load_dwordx4 prefetch (no LDS staging),
//            E/F fp32 LDS. Same pipe-work as R10 (~46us serial sum);
//            targets the ~45us of barrier/lockstep stall.
// Accounting: R10 gatt5 ~91us matched the calibrated 50%-efficiency model.
// ---------------------------------------------------------------------------

#define LOG2E 1.44269504f

typedef __attribute__((ext_vector_type(8))) short short8;   // 8 bf16 = 4 VGPRs
typedef __attribute__((ext_vector_type(4))) float floatx4;  // MFMA acc

using uint_as1 = __attribute__((address_space(1))) unsigned int;
using uint_as3 = __attribute__((address_space(3))) unsigned int;

__device__ __forceinline__ void gld_lds16(const void* g, void* l) {
  __builtin_amdgcn_global_load_lds((const uint_as1*)g, (uint_as3*)l, 16, 0, 0);
}

__device__ __forceinline__ unsigned short f2b(float f) {  // fp32 -> bf16 RNE (finite)
  unsigned u = __float_as_uint(f);
  u += 0x7fffu + ((u >> 16) & 1u);
  return (unsigned short)(u >> 16);
}
__device__ __forceinline__ float b2f(short s) {
  return __uint_as_float(((unsigned)(unsigned short)s) << 16);
}

// -------- K_bmz: adj -> bitmask + Z rowsums (one wave per row) -------------
__global__ void k_bitmaskz(const int* __restrict__ adj,
                           const float* __restrict__ Emu, const float* __restrict__ Fmu,
                           const float* __restrict__ Exi, const float* __restrict__ Fxi,
                           unsigned long long* __restrict__ bm, float* __restrict__ zbuf) {
  int gw = (blockIdx.x * 256 + threadIdx.x) >> 6;   // row i
  int lane = threadIdx.x & 63;
  float EM = Emu[gw], FM = Fmu[gw];
  size_t w0 = (size_t)gw * 128;
  float z = 0.f;
  for (int r = 0; r < 128; r += 4) {
    size_t wd = w0 + r;
    int v0 = adj[(wd + 0) * 64 + lane];
    int v1 = adj[(wd + 1) * 64 + lane];
    int v2 = adj[(wd + 2) * 64 + lane];
    int v3 = adj[(wd + 3) * 64 + lane];
    float e0 = Exi[(r + 0) * 64 + lane], f0 = Fxi[(r + 0) * 64 + lane];
    float e1 = Exi[(r + 1) * 64 + lane], f1 = Fxi[(r + 1) * 64 + lane];
    float e2 = Exi[(r + 2) * 64 + lane], f2 = Fxi[(r + 2) * 64 + lane];
    float e3 = Exi[(r + 3) * 64 + lane], f3 = Fxi[(r + 3) * 64 + lane];
    unsigned long long m0 = __ballot(v0 != 0);
    unsigned long long m1 = __ballot(v1 != 0);
    unsigned long long m2 = __ballot(v2 != 0);
    unsigned long long m3 = __ballot(v3 != 0);
    z += (v0 != 0) ? fmaxf(EM * e0, FM * f0) : 0.f;
    z += (v1 != 0) ? fmaxf(EM * e1, FM * f1) : 0.f;
    z += (v2 != 0) ? fmaxf(EM * e2, FM * f2) : 0.f;
    z += (v3 != 0) ? fmaxf(EM * e3, FM * f3) : 0.f;
    if (lane == 0) {
      bm[wd] = m0; bm[wd + 1] = m1; bm[wd + 2] = m2; bm[wd + 3] = m3;
    }
  }
#pragma unroll
  for (int off = 32; off > 0; off >>= 1) z += __shfl_xor(z, off);
  if (lane == 0) zbuf[gw] = z;
}

// --------------------------- K0a: features -> bf16 -------------------------
__global__ void k_cvt_features(const float* __restrict__ f, unsigned short* __restrict__ fb) {
  int tid = blockIdx.x * 256 + threadIdx.x;
  float4 v = ((const float4*)f)[tid];
  ushort4 o = {f2b(v.x), f2b(v.y), f2b(v.z), f2b(v.w)};
  *(ushort4*)&fb[tid * 4] = o;
}

// ------------------- K0b: W_phi [512][256] -> Wt bf16 [256][512] ------------
__global__ void k_prep_wt(const float* __restrict__ w, unsigned short* __restrict__ wt) {
  int tid = blockIdx.x * 256 + threadIdx.x;
  int n = tid >> 9, k = tid & 511;
  wt[n * 512 + k] = f2b(w[k * 256 + n]);
}

// ----------------- K0c: p_mu = W_phi @ w_mu, p_xi = W_phi @ w_xi ------------
__global__ void k_prep_p(const float* __restrict__ w, const float* __restrict__ wmu,
                         const float* __restrict__ wxi, float* __restrict__ pmu,
                         float* __restrict__ pxi) {
  int tid = blockIdx.x * 256 + threadIdx.x;
  int k = tid >> 2, seg = tid & 3;
  float sm = 0.f, sx = 0.f;
  int base = k * 256 + seg * 64;
#pragma unroll
  for (int c = 0; c < 64; c += 4) {
    float4 wv = *(const float4*)&w[base + c];
    float4 mv = *(const float4*)&wmu[seg * 64 + c];
    float4 xv = *(const float4*)&wxi[seg * 64 + c];
    sm += wv.x * mv.x + wv.y * mv.y + wv.z * mv.z + wv.w * mv.w;
    sx += wv.x * xv.x + wv.y * xv.y + wv.z * xv.z + wv.w * xv.w;
  }
  sm += __shfl_xor(sm, 1); sm += __shfl_xor(sm, 2);
  sx += __shfl_xor(sx, 1); sx += __shfl_xor(sx, 2);
  if (seg == 0) { pmu[k] = sm; pxi[k] = sx; }
}

// --- K2: mu/xi matvec, then store Emu=e^mu, Fmu=e^0.2mu, Exi, Fxi -----------
__global__ void k_mu_xi(const unsigned short* __restrict__ fb, const float* __restrict__ pmu,
                        const float* __restrict__ pxi, float* __restrict__ Emu,
                        float* __restrict__ Fmu, float* __restrict__ Exi,
                        float* __restrict__ Fxi) {
  int w = threadIdx.x >> 6, l = threadIdx.x & 63;
  int i = blockIdx.x * 4 + w;
  short8 fv = *(const short8*)&fb[i * 512 + l * 8];
  float m = 0.f, x = 0.f;
#pragma unroll
  for (int c = 0; c < 8; ++c) {
    float fvf = b2f(fv[c]);
    m = fmaf(fvf, pmu[l * 8 + c], m);
    x = fmaf(fvf, pxi[l * 8 + c], x);
  }
#pragma unroll
  for (int off = 32; off > 0; off >>= 1) {
    m += __shfl_xor(m, off);
    x += __shfl_xor(x, off);
  }
  if (l == 0) {
    float ms = m * LOG2E, xs = x * LOG2E;
    Emu[i] = __builtin_amdgcn_exp2f(ms);
    Fmu[i] = __builtin_amdgcn_exp2f(0.2f * ms);
    Exi[i] = __builtin_amdgcn_exp2f(xs);
    Fxi[i] = __builtin_amdgcn_exp2f(0.2f * xs);
  }
}

// ------------- K1: h_t[n][m] = (features @ W_phi)^T, bf16 MFMA --------------
__global__ __launch_bounds__(256, 2) void k_gemm1(const unsigned short* __restrict__ fb,
                                                  const unsigned short* __restrict__ wt,
                                                  unsigned short* __restrict__ ht) {
  __shared__ __align__(16) unsigned short As[64 * 64];
  __shared__ __align__(16) unsigned short Bs[128 * 64];
  int t = threadIdx.x, w = t >> 6, l = t & 63;
  int bm_ = blockIdx.x >> 1, bn = blockIdx.x & 1;
  int m0 = bm_ * 64, n0 = bn * 128;
  int lr = l >> 3, lg = l & 7, g = lg ^ lr;
  int kg = l >> 4, ln = l & 15;
  floatx4 zero = {0.f, 0.f, 0.f, 0.f};
  floatx4 acc[4][2];
#pragma unroll
  for (int mf = 0; mf < 4; ++mf)
#pragma unroll
    for (int nf = 0; nf < 2; ++nf) acc[mf][nf] = zero;

  for (int it = 0; it < 8; ++it) {
    int k0 = it * 64;
#pragma unroll
    for (int q = 0; q < 2; ++q) {
      int row = w * 16 + q * 8 + lr;
      const void* gp = fb + (size_t)(m0 + row) * 512 + k0 + g * 8;
      int lb = __builtin_amdgcn_readfirstlane((w * 16 + q * 8) * 64);
      gld_lds16(gp, &As[lb]);
    }
#pragma unroll
    for (int q = 0; q < 4; ++q) {
      int row = w * 32 + q * 8 + lr;
      const void* gp = wt + (size_t)(n0 + row) * 512 + k0 + g * 8;
      int lb = __builtin_amdgcn_readfirstlane((w * 32 + q * 8) * 64);
      gld_lds16(gp, &Bs[lb]);
    }
    __syncthreads();
#pragma unroll
    for (int ks = 0; ks < 2; ++ks) {
      int gg = ks * 4 + kg;
      int swz = (gg ^ (ln & 7)) * 8;
      short8 bfr[2];
#pragma unroll
      for (int nf = 0; nf < 2; ++nf)
        bfr[nf] = *(const short8*)&Bs[(w * 32 + nf * 16 + ln) * 64 + swz];
#pragma unroll
      for (int mf = 0; mf < 4; ++mf) {
        short8 afr = *(const short8*)&As[(mf * 16 + ln) * 64 + swz];
#pragma unroll
        for (int nf = 0; nf < 2; ++nf)
          acc[mf][nf] = __builtin_amdgcn_mfma_f32_16x16x32_bf16(afr, bfr[nf], acc[mf][nf], 0, 0, 0);
      }
    }
    __syncthreads();
  }
#pragma unroll
  for (int mf = 0; mf < 4; ++mf)
#pragma unroll
    for (int nf = 0; nf < 2; ++nf) {
      int ng = n0 + w * 32 + nf * 16 + ln;
      int mg = m0 + mf * 16 + kg * 4;
      ushort4 o = {f2b(acc[mf][nf][0]), f2b(acc[mf][nf][1]),
                   f2b(acc[mf][nf][2]), f2b(acc[mf][nf][3])};
      *(ushort4*)&ht[(size_t)ng * 8192 + mg] = o;
    }
}

// ------------- K3: attention GEMM, 128j windows, 8 barriers -----------------
// grid 256 = 8 jb x 32 ig. Block 256i x 256n x 1024j; 8 waves i-split,
// wave 32i x 256n (mf=2, nf=16 in halves), acc[2][16]=128 VGPR.
// Bs dbuf 2x64KB; E/F fp32 16KB (144KB LDS, 1 block/CU). Bits: one
// global dwordx4 (128 bits) per (mf,window), register-prefetched.
__global__ __launch_bounds__(512, 2) void k_gatt6(const unsigned char* __restrict__ bm8,
                                                  const unsigned short* __restrict__ ht,
                                                  const float* __restrict__ Emu,
                                                  const float* __restrict__ Fmu,
                                                  const float* __restrict__ Exi,
                                                  const float* __restrict__ Fxi,
                                                  float* __restrict__ nump) {
  __shared__ __align__(16) unsigned short Bs[2][256 * 128];  // 128 KB
  __shared__ __align__(16) float EfE[1024];                  // 8 KB
  __shared__ __align__(16) float EfF[1024];                  // 8 KB

  int t = threadIdx.x, w = t >> 6, l = t & 63;
  int ln = l & 15, kg = l >> 4;
  int jb = blockIdx.x & 7, ig = blockIdx.x >> 3;
  int i0 = ig * 256;
  int jc0 = jb * 1024;

  // ---- prologue: E/F staging (all 512 threads) ----
  if (t < 256) {
    *(float4*)&EfE[t * 4] = *(const float4*)&Exi[jc0 + t * 4];
  } else {
    int t2 = t - 256;
    *(float4*)&EfF[t2 * 4] = *(const float4*)&Fxi[jc0 + t2 * 4];
  }

  float EM[2], FM[2];
  const uint4* bprow[2];
#pragma unroll
  for (int mf = 0; mf < 2; ++mf) {
    int i = i0 + w * 32 + mf * 16 + ln;
    EM[mf] = Emu[i];
    FM[mf] = Fmu[i];
    // 16B per 128-j window: row base + jb*128 bytes, window stride 16B
    bprow[mf] = (const uint4*)(bm8 + (size_t)i * 1024 + jb * 128);
  }

  floatx4 zero = {0.f, 0.f, 0.f, 0.f};
  floatx4 acc[2][16];
#pragma unroll
  for (int mf = 0; mf < 2; ++mf)
#pragma unroll
    for (int nf = 0; nf < 16; ++nf) acc[mf][nf] = zero;

  // stage Bs window win_ (128j x 256n) into buffer b_: 8 rounds/wave
#define STAGE(win_, b_)                                                       \
  {                                                                           \
    int j0_ = jc0 + (win_) * 128;                                             \
    _Pragma("unroll")                                                         \
    for (int q = 0; q < 8; ++q) {                                             \
      int r0 = w * 32 + q * 4;                                                \
      int row = r0 + (l >> 4);                                                \
      int g = (l & 15) ^ (row & 15);                                          \
      const void* gp = ht + (size_t)row * 8192 + j0_ + g * 8;                 \
      int lb = __builtin_amdgcn_readfirstlane((b_) * (256 * 128) + r0 * 128); \
      gld_lds16(gp, &Bs[0][lb]);                                              \
    }                                                                         \
  }

  uint4 bc[2], bnx[2];
#pragma unroll
  for (int mf = 0; mf < 2; ++mf) bc[mf] = bprow[mf][0];
  STAGE(0, 0);
  __syncthreads();  // E/F + staging(0) drained

  for (int win = 0; win < 8; ++win) {
    int buf = win & 1;
    if (win < 7) {
      STAGE(win + 1, buf ^ 1);  // overlaps compute on buf
#pragma unroll
      for (int mf = 0; mf < 2; ++mf) bnx[mf] = bprow[mf][win + 1];
    }
#pragma unroll
    for (int ksl = 0; ksl < 4; ++ksl) {
      int gran = ksl * 4 + kg;            // granule 0..15 within 128j
      int jl = win * 128 + gran * 8;
      float4 e0 = *(const float4*)&EfE[jl];
      float4 e1 = *(const float4*)&EfE[jl + 4];
      float4 f0 = *(const float4*)&EfF[jl];
      float4 f1 = *(const float4*)&EfF[jl + 4];
      float ex[8] = {e0.x, e0.y, e0.z, e0.w, e1.x, e1.y, e1.z, e1.w};
      float fx[8] = {f0.x, f0.y, f0.z, f0.w, f1.x, f1.y, f1.z, f1.w};
      // build A-frags: byte gran of bc[mf]; gran>>2 == ksl (compile-time word)
      short8 af[2];
#pragma unroll
      for (int mf = 0; mf < 2; ++mf) {
        unsigned word = (ksl == 0) ? bc[mf].x : (ksl == 1) ? bc[mf].y
                      : (ksl == 2) ? bc[mf].z : bc[mf].w;
        unsigned bits = (word >> (kg * 8)) & 0xffu;
        float A = EM[mf], F = FM[mf];
#pragma unroll
        for (int e = 0; e < 8; ++e) {
          float m = fmaxf(A * ex[e], F * fx[e]);
          m = (bits & (1u << e)) ? m : 0.f;
          af[mf][e] = (short)f2b(m);
        }
      }
      // two halves of 8 B-frags (limits live VGPRs)
#pragma unroll
      for (int half = 0; half < 2; ++half) {
        short8 bfv[8];
#pragma unroll
        for (int nf = 0; nf < 8; ++nf) {
          int n = half * 128 + nf * 16 + ln;
          bfv[nf] = *(const short8*)&Bs[buf][n * 128 + ((gran ^ (n & 15)) * 8)];
        }
#pragma unroll
        for (int mf = 0; mf < 2; ++mf)
#pragma unroll
          for (int nf = 0; nf < 8; ++nf)
            acc[mf][half * 8 + nf] = __builtin_amdgcn_mfma_f32_16x16x32_bf16(
                af[mf], bfv[nf], acc[mf][half * 8 + nf], 0, 0, 0);
      }
    }
    __syncthreads();  // reads of buf done; staging(win+1) drained
#pragma unroll
    for (int mf = 0; mf < 2; ++mf) bc[mf] = bnx[mf];
  }
#undef STAGE

  // ---- epilogue: numerator partial (plain stores) ----
  float* np = nump + (size_t)jb * (8192 * 256);
#pragma unroll
  for (int mf = 0; mf < 2; ++mf) {
    int rowb = i0 + w * 32 + mf * 16 + kg * 4;
#pragma unroll
    for (int r = 0; r < 4; ++r) {
      float* rp = np + (size_t)(rowb + r) * 256;
#pragma unroll
      for (int nf = 0; nf < 16; ++nf)
        rp[nf * 16 + ln] = acc[mf][nf][r];
    }
  }
}

// ---------------- K4: finalize: sum 8 j-partials, /Z, ELU -------------------
__global__ void k_final(const float* __restrict__ nump, const float* __restrict__ zbuf,
                        float* __restrict__ out) {
  int tid = blockIdx.x * 256 + threadIdx.x;  // x4 floats
  int i = tid >> 6;
  float zi = 1.0f / zbuf[i];
  float4 v = {0.f, 0.f, 0.f, 0.f};
#pragma unroll
  for (int p = 0; p < 8; ++p) {
    float4 s = *(const float4*)&nump[(size_t)p * (8192 * 256) + tid * 4];
    v.x += s.x; v.y += s.y; v.z += s.z; v.w += s.w;
  }
  v.x *= zi; v.y *= zi; v.z *= zi; v.w *= zi;
  v.x = (v.x > 0.f) ? v.x : (__builtin_amdgcn_exp2f(v.x * LOG2E) - 1.f);
  v.y = (v.y > 0.f) ? v.y : (__builtin_amdgcn_exp2f(v.y * LOG2E) - 1.f);
  v.z = (v.z > 0.f) ? v.z : (__builtin_amdgcn_exp2f(v.z * LOG2E) - 1.f);
  v.w = (v.w > 0.f) ? v.w : (__builtin_amdgcn_exp2f(v.w * LOG2E) - 1.f);
  *(float4*)&out[tid * 4] = v;
}

// ---------------------------------------------------------------------------
extern "C" void kernel_launch(void* const* d_in, const int* in_sizes, int n_in,
                              void* d_out, int out_size, void* d_ws, size_t ws_size,
                              hipStream_t stream) {
  const float* features = (const float*)d_in[0];
  const int* adjm = (const int*)d_in[1];
  const float* W_phi = (const float*)d_in[2];
  const float* w_mu = (const float*)d_in[3];
  const float* w_xi = (const float*)d_in[4];
  float* out = (float*)d_out;

  char* ws = (char*)d_ws;
  unsigned short* fb  = (unsigned short*)(ws + 0);         // 8192x512 bf16 = 8 MB
  unsigned short* ht  = (unsigned short*)(ws + 8388608);   // 256x8192 bf16 = 4 MB
  unsigned short* wt  = (unsigned short*)(ws + 12582912);  // 256x512 bf16 = 256 KB
  float* pmu = (float*)(ws + 12845056);                    // 512 f32
  float* pxi = (float*)(ws + 12847104);                    // 512 f32
  float* Emu = (float*)(ws + 12849152);                    // 8192 f32 each
  float* Fmu = (float*)(ws + 12881920);
  float* Exi = (float*)(ws + 12914688);
  float* Fxi = (float*)(ws + 12947456);
  float* zbuf = (float*)(ws + 12980224);                   // 8192 f32
  unsigned char* bmask = (unsigned char*)(ws + 13631488);  // 8 MB bitmask
  float* nump = (float*)(ws + 25165824);                   // 8 x 8 MB partials

  k_cvt_features<<<4096, 256, 0, stream>>>(features, fb);
  k_prep_wt<<<512, 256, 0, stream>>>(W_phi, wt);
  k_prep_p<<<8, 256, 0, stream>>>(W_phi, w_mu, w_xi, pmu, pxi);
  k_mu_xi<<<2048, 256, 0, stream>>>(fb, pmu, pxi, Emu, Fmu, Exi, Fxi);
  k_gemm1<<<256, 256, 0, stream>>>(fb, wt, ht);
  k_bitmaskz<<<2048, 256, 0, stream>>>(adjm, Emu, Fmu, Exi, Fxi,
                                       (unsigned long long*)bmask, zbuf);
  k_gatt6<<<256, 512, 0, stream>>>(bmask, ht, Emu, Fmu, Exi, Fxi, nump);
  k_final<<<2048, 256, 0, stream>>>(nump, zbuf, out);
}